// Round 5
// baseline (20464.778 us; speedup 1.0000x reference)
//
#include <hip/hip_runtime.h>
#include <hip/hip_bf16.h>
#include <hip/hip_cooperative_groups.h>
#include <stdint.h>

// ---------------------------------------------------------------------------
// 2-layer LSTM + linear + CRF NLL on MI355X.
// Round 5: ring READS become normal cached 16-B loads preceded by an
// agent-scope acquire fence (lowers to buffer_inv on gfx95x), so each XCD
// fetches each h slab once/step into L2 instead of every block doing
// uncoalesced uncached 8-B atomic loads (round-4 bottleneck: ~30 us/step of
// fabric serialization, FETCH 8.2 GB). Ring WRITES stay agent-scope
// write-through atomics (never L2-dirty -> post-invalidate reads coherent).
// Schedule (audited): L0 slot s reads h0[s-1], writes h0[s]; L1 slot s reads
// h0[s] + h1[s-1], writes h1[s]. L1 waits c0>=128(s+2) (L0 done slot s);
// L0 waits c1>=128s (L1 done slot s-2) -> L0 <=2 ahead, 2 slabs suffice.
// ---------------------------------------------------------------------------

namespace cg = cooperative_groups;

typedef __bf16 bf16x8 __attribute__((ext_vector_type(8)));
typedef float f32x4 __attribute__((ext_vector_type(4)));

__device__ __forceinline__ f32x4 mfma16(bf16x8 a, bf16x8 b, f32x4 c) {
  return __builtin_amdgcn_mfma_f32_16x16x32_bf16(a, b, c, 0, 0, 0);
}

__device__ __forceinline__ unsigned short f2bf(float f) {
  unsigned u = __float_as_uint(f);
  u = u + 0x7fffu + ((u >> 16) & 1u);
  return (unsigned short)(u >> 16);
}
__device__ __forceinline__ float sigf(float x) { return 1.f / (1.f + __expf(-x)); }
__device__ __forceinline__ float tanh_s(float x) {
  float a = fabsf(x);
  float e = __expf(2.f * a);
  float r = 1.f - 2.f / (e + 1.f);
  return copysignf(r, x);
}
__device__ __forceinline__ bf16x8 cvt8(const float* p) {
  float4 a = *(const float4*)p;
  float4 b = *(const float4*)(p + 4);
  union { bf16x8 v; unsigned short u[8]; } r;
  r.u[0] = f2bf(a.x); r.u[1] = f2bf(a.y); r.u[2] = f2bf(a.z); r.u[3] = f2bf(a.w);
  r.u[4] = f2bf(b.x); r.u[5] = f2bf(b.y); r.u[6] = f2bf(b.z); r.u[7] = f2bf(b.w);
  return r.v;
}

// ---- agent-scope (LLC-coherent) primitives: barrier + ring writes ----
__device__ __forceinline__ unsigned ald32(const unsigned* p) {
  return __hip_atomic_load(p, __ATOMIC_RELAXED, __HIP_MEMORY_SCOPE_AGENT);
}
__device__ __forceinline__ void aadd32(unsigned* p) {
  __hip_atomic_fetch_add(p, 1u, __ATOMIC_RELAXED, __HIP_MEMORY_SCOPE_AGENT);
}
__device__ __forceinline__ void ast32(void* p, unsigned v) {
  __hip_atomic_store((unsigned*)p, v, __ATOMIC_RELAXED, __HIP_MEMORY_SCOPE_AGENT);
}
__device__ __forceinline__ void ast64(void* p, unsigned long long v) {
  __hip_atomic_store((unsigned long long*)p, v, __ATOMIC_RELAXED,
                     __HIP_MEMORY_SCOPE_AGENT);
}

// ---------------------------------------------------------------------------
__global__ void fallback_k(float* out, unsigned wsmb) { *out = -(float)wsmb; }

__global__ void cvt_bf16(const float* __restrict__ in, unsigned short* __restrict__ out, int n) {
  int i = (blockIdx.x * 256 + threadIdx.x) * 4;
  if (i < n) {
    float4 v = *(const float4*)(in + i);
    ushort4 o;
    o.x = f2bf(v.x); o.y = f2bf(v.y); o.z = f2bf(v.z); o.w = f2bf(v.w);
    *(ushort4*)(out + i) = o;
  }
}

__global__ void add_vec(const float* __restrict__ a, const float* __restrict__ b,
                        float* __restrict__ o, int n) {
  int i = blockIdx.x * 256 + threadIdx.x;
  if (i < n) o[i] = a[i] + b[i];
}

// ---------------------------------------------------------------------------
// Fused 2-layer persistent scan, custom barriers.
// MFMA roles: A = W rows (m = jj*4 + gate -> lane holds all 4 gates of one
// (batch, hidden) pair in D regs), B = h / x.
// A-frag: lane m=lane&15, k=(lane>>4)*8+i. B-frag: lane n=lane&15 (batch),
// k=(lane>>4)*8+i. C/D: col(n)=lane&15, row(m)=(lane>>4)*4+reg.
#define BS(mi, ks) (*(const bf16x8*)&Bsm[(((mi)*2048 + (ks)*64 + lane)) * 8])

__global__ __launch_bounds__(256, 1) void lstm_fused(
    const float* __restrict__ x,              // [64][512][512] fp32
    const unsigned short* __restrict__ Whh0b, const unsigned short* __restrict__ Wih0b,
    const unsigned short* __restrict__ Whh1b, const unsigned short* __restrict__ Wih1b,
    const float* __restrict__ bias0, const float* __restrict__ bias1,
    unsigned short* __restrict__ h1_all,      // [64][512][1024] bf16
    unsigned short* h0r, unsigned short* h1r, // [2][64][1024] rings
    unsigned* c0, unsigned* c1)
{
  __shared__ __align__(16) unsigned short Bsm[32768];   // 64 KB Whh A-frags
  const int tid = threadIdx.x;
  const int lane = tid & 63;
  const int w = tid >> 6;            // wave = 16-batch tile
  const int c16 = lane & 15, rg = lane >> 4;
  const bool is1 = blockIdx.x >= 128;
  const int j0 = (is1 ? (int)blockIdx.x - 128 : (int)blockIdx.x) * 8;

  // ---- LDS: Whh A-frags. unit u = mi*2048 + ks*64 + ln; ln is the MFMA lane:
  // m=ln&15 -> (gate=m&3, jj=m>>2); k = ks*32 + (ln>>4)*8.
  {
    const unsigned short* W = is1 ? Whh1b : Whh0b;
    for (int u = tid; u < 4096; u += 256) {
      int mi = u >> 11;
      int ks = (u >> 6) & 31;
      int ln = u & 63;
      int m = ln & 15;
      long row = (long)(m & 3) * 1024 + j0 + mi * 4 + (m >> 2);
      *(bf16x8*)&Bsm[u * 8] = *(const bf16x8*)(W + row * 1024 + ks * 32 + (ln >> 4) * 8);
    }
  }
  // ---- Registers: Wih A-frags (L0: K=512 -> 2x16; L1: K=1024 -> 2x32) ----
  bf16x8 wf[2][32];
  {
    const int g = c16 & 3, jj = c16 >> 2;
    if (is1) {
#pragma unroll
      for (int mi = 0; mi < 2; ++mi) {
        long row = (long)g * 1024 + j0 + mi * 4 + jj;
#pragma unroll
        for (int ks = 0; ks < 32; ++ks)
          wf[mi][ks] = *(const bf16x8*)(Wih1b + row * 1024 + ks * 32 + rg * 8);
      }
    } else {
#pragma unroll
      for (int mi = 0; mi < 2; ++mi) {
        long row = (long)g * 1024 + j0 + mi * 4 + jj;
#pragma unroll
        for (int ks = 0; ks < 16; ++ks)
          wf[mi][ks] = *(const bf16x8*)(Wih0b + row * 512 + ks * 32 + rg * 8);
      }
    }
  }
  // ---- biases: bs[mi][r] = bias[r*1024 + j] ----
  const float* bias = is1 ? bias1 : bias0;
  float bs[2][4];
#pragma unroll
  for (int mi = 0; mi < 2; ++mi)
#pragma unroll
    for (int r = 0; r < 4; ++r) bs[mi][r] = bias[r * 1024 + j0 + mi * 4 + rg];

  // ---- zero own slice of slab 1 of own ring (read as h[-1]), LLC stores ----
  unsigned short* ring = is1 ? h1r : h0r;
  if (tid < 128) ast64(ring + 65536 + (tid >> 1) * 1024 + j0 + (tid & 1) * 4, 0ull);
  __syncthreads();                       // drains vmcnt for all waves
  if (tid == 0) aadd32(is1 ? c1 : c0);   // zero-epoch arrival

  const int boff = (w * 16 + c16) * 1024;
  const int koffbase = rg * 8;
  float cst[2] = {0.f, 0.f};
  const f32x4 fz = {0.f, 0.f, 0.f, 0.f};

  for (int s = 0; s < 512; ++s) {
    // L0: prefetch x frags (barrier-independent)
    bf16x8 xa[16];
    if (!is1) {
      const float* xp = x + ((long)(w * 16 + c16) * 512 + s) * 512 + koffbase;
#pragma unroll
      for (int ks = 0; ks < 16; ++ks) xa[ks] = cvt8(xp + ks * 32);
    }
    // ---- wait ----
    if (tid == 0) {
      if (!is1) {
        while (ald32(c0) < 128u * (s + 1)) __builtin_amdgcn_s_sleep(2);
        if (s >= 2)
          while (ald32(c1) < 128u * s) __builtin_amdgcn_s_sleep(2);
      } else {
        while (ald32(c1) < 128u * (s + 1)) __builtin_amdgcn_s_sleep(2);
        while (ald32(c0) < 128u * (s + 2)) __builtin_amdgcn_s_sleep(2);
      }
    }
    __syncthreads();
    // Invalidate stale clean L1/L2 lines (ring slabs from 2 steps ago), then
    // read rings with NORMAL cached loads. Ring writes are write-through
    // atomics, so caches post-invalidate are coherent with IC.
    __builtin_amdgcn_fence(__ATOMIC_ACQUIRE, "agent");

    f32x4 aW0 = fz, aW1 = fz, aI0 = fz, aI1 = fz;
    const unsigned short* hprev = ring + ((s + 1) & 1) * 65536 + boff + koffbase;
    if (!is1) {
#pragma unroll 8
      for (int ks = 0; ks < 32; ++ks) {
        bf16x8 hb = *(const bf16x8*)(hprev + ks * 32);
        aW0 = mfma16(BS(0, ks), hb, aW0);
        aW1 = mfma16(BS(1, ks), hb, aW1);
      }
#pragma unroll
      for (int ks = 0; ks < 16; ++ks) {
        aI0 = mfma16(wf[0][ks], xa[ks], aI0);
        aI1 = mfma16(wf[1][ks], xa[ks], aI1);
      }
    } else {
      const unsigned short* h0p = h0r + (s & 1) * 65536 + boff + koffbase;
#pragma unroll 8
      for (int ks = 0; ks < 32; ++ks) {
        bf16x8 hb = *(const bf16x8*)(hprev + ks * 32);
        bf16x8 h0b = *(const bf16x8*)(h0p + ks * 32);
        aW0 = mfma16(BS(0, ks), hb, aW0);
        aW1 = mfma16(BS(1, ks), hb, aW1);
        aI0 = mfma16(wf[0][ks], h0b, aI0);
        aI1 = mfma16(wf[1][ks], h0b, aI1);
      }
    }
    // ---- gates (lane-local), cell update, packed 32-bit write-through store ----
    unsigned short* rout = ring + (s & 1) * 65536;
    const int b = w * 16 + c16;
#pragma unroll
    for (int mi = 0; mi < 2; ++mi) {
      float p_i = (mi ? aW1[0] + aI1[0] : aW0[0] + aI0[0]) + bs[mi][0];
      float p_f = (mi ? aW1[1] + aI1[1] : aW0[1] + aI0[1]) + bs[mi][1];
      float p_g = (mi ? aW1[2] + aI1[2] : aW0[2] + aI0[2]) + bs[mi][2];
      float p_o = (mi ? aW1[3] + aI1[3] : aW0[3] + aI0[3]) + bs[mi][3];
      float iv = sigf(p_i);
      float fv = sigf(p_f);
      float gv = tanh_s(p_g);
      float ov = sigf(p_o);
      float cn = fv * cst[mi] + iv * gv;
      cst[mi] = cn;
      float hv = ov * tanh_s(cn);
      unsigned hu = f2bf(hv);
      int j = j0 + mi * 4 + rg;
      // pack with rg-parity partner (lane ^ 16): even rg stores (even j low)
      unsigned pu = (unsigned)__shfl_xor((int)hu, 16);
      if ((rg & 1) == 0) ast32(rout + b * 1024 + j, hu | (pu << 16));
      if (is1) h1_all[((long)b * 512 + s) * 1024 + j] = (unsigned short)hu;
    }
    __syncthreads();                         // drain all waves' ring stores
    if (tid == 0) aadd32(is1 ? c1 : c0);     // slot arrival
  }
}

// ---------------------------------------------------------------------------
// emissions[m][c] = h1[m][:] . fc_w[c][:] + fc_b[c], c<20 (N padded to 32).
__global__ __launch_bounds__(256) void emis_k(
    const unsigned short* __restrict__ h1, const unsigned short* __restrict__ fcw,
    const float* __restrict__ fcb, float* __restrict__ em) {
  __shared__ __align__(16) unsigned short Bsm[32768];
  const int tid = threadIdx.x;
  const int lane = tid & 63;
  const int w = tid >> 6;
  const int c16 = lane & 15, rg = lane >> 4;
  for (int u = tid; u < 4096; u += 256) {
    int tile = u >> 11;
    int ks = (u >> 6) & 31;
    int ln = u & 63;
    int n = tile * 16 + (ln & 15);
    int kb = ks * 32 + (ln >> 4) * 8;
    if (n < 20) {
      *(bf16x8*)&Bsm[u * 8] = *(const bf16x8*)(fcw + (long)n * 1024 + kb);
    } else {
#pragma unroll
      for (int j = 0; j < 8; ++j) Bsm[u * 8 + j] = 0;
    }
  }
  __syncthreads();
  const long r0 = (long)blockIdx.x * 64;
  const bf16x8* arow = (const bf16x8*)(h1 + (r0 + w * 16 + c16) * 1024 + rg * 8);
  const f32x4 fz = {0.f, 0.f, 0.f, 0.f};
  f32x4 acc0 = fz, acc1 = fz;
#pragma unroll 4
  for (int ks = 0; ks < 32; ++ks) {
    bf16x8 a = arow[ks * 4];
    acc0 = mfma16(a, *(const bf16x8*)&Bsm[(ks * 64 + lane) * 8], acc0);
    acc1 = mfma16(a, *(const bf16x8*)&Bsm[((32 + ks) * 64 + lane) * 8], acc1);
  }
#pragma unroll
  for (int r = 0; r < 4; ++r) {
    long row = r0 + w * 16 + rg * 4 + r;
    em[row * 20 + c16] = acc0[r] + fcb[c16];
    int col1 = 16 + c16;
    if (col1 < 20) em[row * 20 + col1] = acc1[r] + fcb[col1];
  }
}

// ---------------------------------------------------------------------------
// CRF NLL: one wave per batch. Lanes 0..19 hold alpha[j]; 511 serial steps.
__global__ __launch_bounds__(256) void crf_k(
    const float* __restrict__ em, const int* __restrict__ labels,
    const float* __restrict__ startt, const float* __restrict__ endt,
    const float* __restrict__ trans, float* __restrict__ out) {
  const int lane = threadIdx.x & 63;
  const int b = blockIdx.x * 4 + (threadIdx.x >> 6);
  const float NEG = -1e30f;
  const int j = lane;
  const bool act = j < 20;
  float treg[20];
#pragma unroll
  for (int i = 0; i < 20; ++i) treg[i] = act ? trans[i * 20 + j] : 0.f;
  const float* emb = em + (long)b * 512 * 20;
  const int* lab = labels + (long)b * 512;
  float alpha = act ? (startt[j] + emb[j]) : NEG;
  for (int t = 1; t < 512; ++t) {
    float mx = NEG;
#pragma unroll
    for (int i = 0; i < 20; ++i) {
      float v = __shfl(alpha, i) + treg[i];
      mx = fmaxf(mx, v);
    }
    float s = 0.f;
#pragma unroll
    for (int i = 0; i < 20; ++i) {
      float v = __shfl(alpha, i) + treg[i];
      s += __expf(v - mx);
    }
    bool m = lab[t] != -1;
    float na = emb[t * 20 + (act ? j : 0)] + mx + __logf(s);
    if (act && m) alpha = na;
  }
  float v = act ? (alpha + endt[j]) : NEG;
  float mx = v;
#pragma unroll
  for (int o = 32; o > 0; o >>= 1) mx = fmaxf(mx, __shfl_xor(mx, o));
  float s = act ? __expf(v - mx) : 0.f;
#pragma unroll
  for (int o = 32; o > 0; o >>= 1) s += __shfl_xor(s, o);
  float logZ = mx + __logf(s);
  float part = 0.f;
  int cntm = 0;
  for (int t = lane; t < 512; t += 64) cntm += (lab[t] != -1) ? 1 : 0;
  for (int t = 1 + lane; t < 512; t += 64) {
    int tg = lab[t];
    if (tg != -1) {
      int tp = lab[t - 1];
      int tgc = min(max(tg, 0), 19);
      int tpc = min(max(tp, 0), 19);
      part += trans[tpc * 20 + tgc] + emb[t * 20 + tgc];
    }
  }
#pragma unroll
  for (int o = 32; o > 0; o >>= 1) {
    part += __shfl_xor(part, o);
    cntm += __shfl_xor(cntm, o);
  }
  if (lane == 0) {
    int t0c = min(max(lab[0], 0), 19);
    float score = startt[t0c] + emb[t0c] + part;
    int last = max(cntm - 1, 0);
    int tlc = min(max(lab[last], 0), 19);
    score += endt[tlc];
    float llh = score - logZ;
    atomicAdd(out, llh * (-1.f / 64.f));
  }
}

// ---------------------------------------------------------------------------
extern "C" void kernel_launch(void* const* d_in, const int* in_sizes, int n_in,
                              void* d_out, int out_size, void* d_ws, size_t ws_size,
                              hipStream_t stream) {
  const float* x      = (const float*)d_in[0];
  const int* labels   = (const int*)d_in[1];
  const float* Wih0   = (const float*)d_in[3];
  const float* Whh0   = (const float*)d_in[4];
  const float* bih0   = (const float*)d_in[5];
  const float* bhh0   = (const float*)d_in[6];
  const float* Wih1   = (const float*)d_in[7];
  const float* Whh1   = (const float*)d_in[8];
  const float* bih1   = (const float*)d_in[9];
  const float* bhh1   = (const float*)d_in[10];
  const float* fcw    = (const float*)d_in[11];
  const float* fcb    = (const float*)d_in[12];
  const float* startt = (const float*)d_in[13];
  const float* endt   = (const float*)d_in[14];
  const float* trans  = (const float*)d_in[15];
  float* out = (float*)d_out;

  char* ws = (char*)d_ws;
  size_t off = 0;
  auto alloc = [&](size_t bytes) -> void* {
    void* p = ws + off;
    off = (off + bytes + 255) & ~(size_t)255;
    return p;
  };
  unsigned short* h1_all = (unsigned short*)alloc(33554432ull * 2);  // 64 MB
  unsigned short* Whh0_b = (unsigned short*)alloc(4194304ull * 2);
  unsigned short* Wih0_b = (unsigned short*)alloc(2097152ull * 2);
  unsigned short* Whh1_b = (unsigned short*)alloc(4194304ull * 2);
  unsigned short* Wih1_b = (unsigned short*)alloc(4194304ull * 2);
  unsigned short* fcw_b  = (unsigned short*)alloc(20480ull * 2);
  float* bias0           = (float*)alloc(4096 * 4);
  float* bias1           = (float*)alloc(4096 * 4);
  unsigned short* h0r    = (unsigned short*)alloc(131072ull * 2);
  unsigned short* h1r    = (unsigned short*)alloc(131072ull * 2);
  float* em              = (float*)alloc(32768ull * 20 * 4);
  unsigned* cnts         = (unsigned*)alloc(256);
  unsigned* c0 = cnts;
  unsigned* c1 = cnts + 32;   // separate cacheline

  if (off > ws_size) {
    unsigned wsmb = (unsigned)(ws_size >> 20);
    fallback_k<<<1, 1, 0, stream>>>(out, wsmb);
    return;
  }

  hipMemsetAsync(cnts, 0, 256, stream);
  hipMemsetAsync(d_out, 0, sizeof(float), stream);

  cvt_bf16<<<4096, 256, 0, stream>>>(Whh0, Whh0_b, 4194304);
  cvt_bf16<<<2048, 256, 0, stream>>>(Wih0, Wih0_b, 2097152);
  cvt_bf16<<<4096, 256, 0, stream>>>(Whh1, Whh1_b, 4194304);
  cvt_bf16<<<4096, 256, 0, stream>>>(Wih1, Wih1_b, 4194304);
  cvt_bf16<<<20, 256, 0, stream>>>(fcw, fcw_b, 20480);
  add_vec<<<16, 256, 0, stream>>>(bih0, bhh0, bias0, 4096);
  add_vec<<<16, 256, 0, stream>>>(bih1, bhh1, bias1, 4096);

  {
    void* args[] = {(void*)&x, (void*)&Whh0_b, (void*)&Wih0_b, (void*)&Whh1_b,
                    (void*)&Wih1_b, (void*)&bias0, (void*)&bias1,
                    (void*)&h1_all, (void*)&h0r, (void*)&h1r,
                    (void*)&c0, (void*)&c1};
    hipLaunchCooperativeKernel((void*)lstm_fused, dim3(256), dim3(256), args, 0, stream);
  }
  emis_k<<<512, 256, 0, stream>>>(h1_all, fcw_b, fcb, em);
  crf_k<<<16, 256, 0, stream>>>(em, labels, startt, endt, trans, out);
}

// Round 6
// 18805.859 us; speedup vs baseline: 1.0882x; 1.0882x over previous
//
#include <hip/hip_runtime.h>
#include <hip/hip_bf16.h>
#include <hip/hip_cooperative_groups.h>
#include <stdint.h>

// ---------------------------------------------------------------------------
// 2-layer LSTM + linear + CRF NLL on MI355X.
// Round 6: distributed flag-array barrier. Rounds 3-5 all plateaued at
// ~37-44 us/step regardless of data path => bottleneck is the 128-way
// same-address atomicAdd (RMWs serialize ~300ns each at the coherence point).
// Now: arrival = plain relaxed agent store to own flag slot (parallel,
// no RMW); wait = wave0 polls 128+128 flags in parallel (4 loads/lane),
// then __syncthreads + acquire fence (buffer_inv) before cached ring reads.
// Ring writes stay write-through agent atomics (never L2-dirty).
// Flags: f=1 after init; f=s+2 after slot s.
//   L0 slot s: own f0>=s+1, other f1>=s   (L1 done s-2 released slab s&1)
//   L1 slot s: own f1>=s+1, other f0>=s+2 (L0 done s => h0[s] ready)
// ---------------------------------------------------------------------------

namespace cg = cooperative_groups;

typedef __bf16 bf16x8 __attribute__((ext_vector_type(8)));
typedef float f32x4 __attribute__((ext_vector_type(4)));

__device__ __forceinline__ f32x4 mfma16(bf16x8 a, bf16x8 b, f32x4 c) {
  return __builtin_amdgcn_mfma_f32_16x16x32_bf16(a, b, c, 0, 0, 0);
}

__device__ __forceinline__ unsigned short f2bf(float f) {
  unsigned u = __float_as_uint(f);
  u = u + 0x7fffu + ((u >> 16) & 1u);
  return (unsigned short)(u >> 16);
}
__device__ __forceinline__ float sigf(float x) { return 1.f / (1.f + __expf(-x)); }
__device__ __forceinline__ float tanh_s(float x) {
  float a = fabsf(x);
  float e = __expf(2.f * a);
  float r = 1.f - 2.f / (e + 1.f);
  return copysignf(r, x);
}
__device__ __forceinline__ bf16x8 cvt8(const float* p) {
  float4 a = *(const float4*)p;
  float4 b = *(const float4*)(p + 4);
  union { bf16x8 v; unsigned short u[8]; } r;
  r.u[0] = f2bf(a.x); r.u[1] = f2bf(a.y); r.u[2] = f2bf(a.z); r.u[3] = f2bf(a.w);
  r.u[4] = f2bf(b.x); r.u[5] = f2bf(b.y); r.u[6] = f2bf(b.z); r.u[7] = f2bf(b.w);
  return r.v;
}

// ---- agent-scope (LLC-coherent) primitives ----
__device__ __forceinline__ unsigned ald32(const unsigned* p) {
  return __hip_atomic_load(p, __ATOMIC_RELAXED, __HIP_MEMORY_SCOPE_AGENT);
}
__device__ __forceinline__ void ast32(void* p, unsigned v) {
  __hip_atomic_store((unsigned*)p, v, __ATOMIC_RELAXED, __HIP_MEMORY_SCOPE_AGENT);
}
__device__ __forceinline__ void ast64(void* p, unsigned long long v) {
  __hip_atomic_store((unsigned long long*)p, v, __ATOMIC_RELAXED,
                     __HIP_MEMORY_SCOPE_AGENT);
}

// ---------------------------------------------------------------------------
__global__ void fallback_k(float* out, unsigned wsmb) { *out = -(float)wsmb; }

__global__ void cvt_bf16(const float* __restrict__ in, unsigned short* __restrict__ out, int n) {
  int i = (blockIdx.x * 256 + threadIdx.x) * 4;
  if (i < n) {
    float4 v = *(const float4*)(in + i);
    ushort4 o;
    o.x = f2bf(v.x); o.y = f2bf(v.y); o.z = f2bf(v.z); o.w = f2bf(v.w);
    *(ushort4*)(out + i) = o;
  }
}

__global__ void add_vec(const float* __restrict__ a, const float* __restrict__ b,
                        float* __restrict__ o, int n) {
  int i = blockIdx.x * 256 + threadIdx.x;
  if (i < n) o[i] = a[i] + b[i];
}

// ---------------------------------------------------------------------------
// Fused 2-layer persistent scan, flag-array barriers.
// MFMA roles: A = W rows (m = jj*4 + gate -> lane holds all 4 gates of one
// (batch, hidden) pair in D regs), B = h / x.
#define BS(mi, ks) (*(const bf16x8*)&Bsm[(((mi)*2048 + (ks)*64 + lane)) * 8])

__global__ __launch_bounds__(256, 1) void lstm_fused(
    const float* __restrict__ x,              // [64][512][512] fp32
    const unsigned short* __restrict__ Whh0b, const unsigned short* __restrict__ Wih0b,
    const unsigned short* __restrict__ Whh1b, const unsigned short* __restrict__ Wih1b,
    const float* __restrict__ bias0, const float* __restrict__ bias1,
    unsigned short* __restrict__ h1_all,      // [64][512][1024] bf16
    unsigned short* h0r, unsigned short* h1r, // [2][64][1024] rings
    unsigned* f0, unsigned* f1)               // [128] flags each
{
  __shared__ __align__(16) unsigned short Bsm[32768];   // 64 KB Whh A-frags
  const int tid = threadIdx.x;
  const int lane = tid & 63;
  const int w = tid >> 6;            // wave = 16-batch tile
  const int c16 = lane & 15, rg = lane >> 4;
  const bool is1 = blockIdx.x >= 128;
  const int bid = is1 ? (int)blockIdx.x - 128 : (int)blockIdx.x;
  const int j0 = bid * 8;

  // ---- LDS: Whh A-frags. unit u = mi*2048 + ks*64 + ln; ln is the MFMA lane:
  // m=ln&15 -> (gate=m&3, jj=m>>2); k = ks*32 + (ln>>4)*8.
  {
    const unsigned short* W = is1 ? Whh1b : Whh0b;
    for (int u = tid; u < 4096; u += 256) {
      int mi = u >> 11;
      int ks = (u >> 6) & 31;
      int ln = u & 63;
      int m = ln & 15;
      long row = (long)(m & 3) * 1024 + j0 + mi * 4 + (m >> 2);
      *(bf16x8*)&Bsm[u * 8] = *(const bf16x8*)(W + row * 1024 + ks * 32 + (ln >> 4) * 8);
    }
  }
  // ---- Registers: Wih A-frags (L0: K=512 -> 2x16; L1: K=1024 -> 2x32) ----
  bf16x8 wf[2][32];
  {
    const int g = c16 & 3, jj = c16 >> 2;
    if (is1) {
#pragma unroll
      for (int mi = 0; mi < 2; ++mi) {
        long row = (long)g * 1024 + j0 + mi * 4 + jj;
#pragma unroll
        for (int ks = 0; ks < 32; ++ks)
          wf[mi][ks] = *(const bf16x8*)(Wih1b + row * 1024 + ks * 32 + rg * 8);
      }
    } else {
#pragma unroll
      for (int mi = 0; mi < 2; ++mi) {
        long row = (long)g * 1024 + j0 + mi * 4 + jj;
#pragma unroll
        for (int ks = 0; ks < 16; ++ks)
          wf[mi][ks] = *(const bf16x8*)(Wih0b + row * 512 + ks * 32 + rg * 8);
      }
    }
  }
  // ---- biases: bs[mi][r] = bias[r*1024 + j] ----
  const float* bias = is1 ? bias1 : bias0;
  float bs[2][4];
#pragma unroll
  for (int mi = 0; mi < 2; ++mi)
#pragma unroll
    for (int r = 0; r < 4; ++r) bs[mi][r] = bias[r * 1024 + j0 + mi * 4 + rg];

  // ---- zero own slice of slab 1 of own ring (read as h[-1]) ----
  unsigned short* ring = is1 ? h1r : h0r;
  if (tid < 128) ast64(ring + 65536 + (tid >> 1) * 1024 + j0 + (tid & 1) * 4, 0ull);
  __syncthreads();                                  // drains vmcnt for all waves
  if (tid == 0) ast32((is1 ? f1 : f0) + bid, 1u);   // init arrival

  const unsigned* fown = is1 ? f1 : f0;
  const unsigned* foth = is1 ? f0 : f1;
  const int boff = (w * 16 + c16) * 1024;
  const int koffbase = rg * 8;
  float cst[2] = {0.f, 0.f};
  const f32x4 fz = {0.f, 0.f, 0.f, 0.f};

  for (int s = 0; s < 512; ++s) {
    // L0: prefetch x frags (barrier-independent)
    bf16x8 xa[16];
    if (!is1) {
      const float* xp = x + ((long)(w * 16 + c16) * 512 + s) * 512 + koffbase;
#pragma unroll
      for (int ks = 0; ks < 16; ++ks) xa[ks] = cvt8(xp + ks * 32);
    }
    // ---- wait: wave 0 polls all flags in parallel ----
    if (tid < 64) {
      const unsigned t_own = (unsigned)(s + 1);
      const unsigned t_oth = (unsigned)(is1 ? s + 2 : s);
      for (;;) {
        unsigned a = ald32(fown + lane);
        unsigned b = ald32(fown + lane + 64);
        unsigned c = ald32(foth + lane);
        unsigned d = ald32(foth + lane + 64);
        bool ok = (a >= t_own) & (b >= t_own) & (c >= t_oth) & (d >= t_oth);
        if (__ballot(!ok) == 0ull) break;
        __builtin_amdgcn_s_sleep(2);
      }
    }
    __syncthreads();
    // Invalidate stale clean L1/L2 lines, then read rings with cached loads.
    __builtin_amdgcn_fence(__ATOMIC_ACQUIRE, "agent");

    f32x4 aW0 = fz, aW1 = fz, aI0 = fz, aI1 = fz;
    const unsigned short* hprev = ring + ((s + 1) & 1) * 65536 + boff + koffbase;
    if (!is1) {
#pragma unroll 8
      for (int ks = 0; ks < 32; ++ks) {
        bf16x8 hb = *(const bf16x8*)(hprev + ks * 32);
        aW0 = mfma16(BS(0, ks), hb, aW0);
        aW1 = mfma16(BS(1, ks), hb, aW1);
      }
#pragma unroll
      for (int ks = 0; ks < 16; ++ks) {
        aI0 = mfma16(wf[0][ks], xa[ks], aI0);
        aI1 = mfma16(wf[1][ks], xa[ks], aI1);
      }
    } else {
      const unsigned short* h0p = h0r + (s & 1) * 65536 + boff + koffbase;
#pragma unroll 8
      for (int ks = 0; ks < 32; ++ks) {
        bf16x8 hb = *(const bf16x8*)(hprev + ks * 32);
        bf16x8 h0b = *(const bf16x8*)(h0p + ks * 32);
        aW0 = mfma16(BS(0, ks), hb, aW0);
        aW1 = mfma16(BS(1, ks), hb, aW1);
        aI0 = mfma16(wf[0][ks], h0b, aI0);
        aI1 = mfma16(wf[1][ks], h0b, aI1);
      }
    }
    // ---- gates (lane-local), cell update, packed 32-bit write-through store ----
    unsigned short* rout = ring + (s & 1) * 65536;
    const int b = w * 16 + c16;
#pragma unroll
    for (int mi = 0; mi < 2; ++mi) {
      float p_i = (mi ? aW1[0] + aI1[0] : aW0[0] + aI0[0]) + bs[mi][0];
      float p_f = (mi ? aW1[1] + aI1[1] : aW0[1] + aI0[1]) + bs[mi][1];
      float p_g = (mi ? aW1[2] + aI1[2] : aW0[2] + aI0[2]) + bs[mi][2];
      float p_o = (mi ? aW1[3] + aI1[3] : aW0[3] + aI0[3]) + bs[mi][3];
      float iv = sigf(p_i);
      float fv = sigf(p_f);
      float gv = tanh_s(p_g);
      float ov = sigf(p_o);
      float cn = fv * cst[mi] + iv * gv;
      cst[mi] = cn;
      float hv = ov * tanh_s(cn);
      unsigned hu = f2bf(hv);
      int j = j0 + mi * 4 + rg;
      unsigned pu = (unsigned)__shfl_xor((int)hu, 16);
      if ((rg & 1) == 0) ast32(rout + b * 1024 + j, hu | (pu << 16));
      if (is1) h1_all[((long)b * 512 + s) * 1024 + j] = (unsigned short)hu;
    }
    __syncthreads();                                      // drain ring stores
    if (tid == 0) ast32((unsigned*)(fown + bid), (unsigned)(s + 2));  // arrival
  }
}

// ---------------------------------------------------------------------------
// emissions[m][c] = h1[m][:] . fc_w[c][:] + fc_b[c], c<20 (N padded to 32).
__global__ __launch_bounds__(256) void emis_k(
    const unsigned short* __restrict__ h1, const unsigned short* __restrict__ fcw,
    const float* __restrict__ fcb, float* __restrict__ em) {
  __shared__ __align__(16) unsigned short Bsm[32768];
  const int tid = threadIdx.x;
  const int lane = tid & 63;
  const int w = tid >> 6;
  const int c16 = lane & 15, rg = lane >> 4;
  for (int u = tid; u < 4096; u += 256) {
    int tile = u >> 11;
    int ks = (u >> 6) & 31;
    int ln = u & 63;
    int n = tile * 16 + (ln & 15);
    int kb = ks * 32 + (ln >> 4) * 8;
    if (n < 20) {
      *(bf16x8*)&Bsm[u * 8] = *(const bf16x8*)(fcw + (long)n * 1024 + kb);
    } else {
#pragma unroll
      for (int j = 0; j < 8; ++j) Bsm[u * 8 + j] = 0;
    }
  }
  __syncthreads();
  const long r0 = (long)blockIdx.x * 64;
  const bf16x8* arow = (const bf16x8*)(h1 + (r0 + w * 16 + c16) * 1024 + rg * 8);
  const f32x4 fz = {0.f, 0.f, 0.f, 0.f};
  f32x4 acc0 = fz, acc1 = fz;
#pragma unroll 4
  for (int ks = 0; ks < 32; ++ks) {
    bf16x8 a = arow[ks * 4];
    acc0 = mfma16(a, *(const bf16x8*)&Bsm[(ks * 64 + lane) * 8], acc0);
    acc1 = mfma16(a, *(const bf16x8*)&Bsm[((32 + ks) * 64 + lane) * 8], acc1);
  }
#pragma unroll
  for (int r = 0; r < 4; ++r) {
    long row = r0 + w * 16 + rg * 4 + r;
    em[row * 20 + c16] = acc0[r] + fcb[c16];
    int col1 = 16 + c16;
    if (col1 < 20) em[row * 20 + col1] = acc1[r] + fcb[col1];
  }
}

// ---------------------------------------------------------------------------
// CRF NLL: one wave per batch. Lanes 0..19 hold alpha[j]; 511 serial steps.
__global__ __launch_bounds__(256) void crf_k(
    const float* __restrict__ em, const int* __restrict__ labels,
    const float* __restrict__ startt, const float* __restrict__ endt,
    const float* __restrict__ trans, float* __restrict__ out) {
  const int lane = threadIdx.x & 63;
  const int b = blockIdx.x * 4 + (threadIdx.x >> 6);
  const float NEG = -1e30f;
  const int j = lane;
  const bool act = j < 20;
  float treg[20];
#pragma unroll
  for (int i = 0; i < 20; ++i) treg[i] = act ? trans[i * 20 + j] : 0.f;
  const float* emb = em + (long)b * 512 * 20;
  const int* lab = labels + (long)b * 512;
  float alpha = act ? (startt[j] + emb[j]) : NEG;
  for (int t = 1; t < 512; ++t) {
    float mx = NEG;
#pragma unroll
    for (int i = 0; i < 20; ++i) {
      float v = __shfl(alpha, i) + treg[i];
      mx = fmaxf(mx, v);
    }
    float s = 0.f;
#pragma unroll
    for (int i = 0; i < 20; ++i) {
      float v = __shfl(alpha, i) + treg[i];
      s += __expf(v - mx);
    }
    bool m = lab[t] != -1;
    float na = emb[t * 20 + (act ? j : 0)] + mx + __logf(s);
    if (act && m) alpha = na;
  }
  float v = act ? (alpha + endt[j]) : NEG;
  float mx = v;
#pragma unroll
  for (int o = 32; o > 0; o >>= 1) mx = fmaxf(mx, __shfl_xor(mx, o));
  float s = act ? __expf(v - mx) : 0.f;
#pragma unroll
  for (int o = 32; o > 0; o >>= 1) s += __shfl_xor(s, o);
  float logZ = mx + __logf(s);
  float part = 0.f;
  int cntm = 0;
  for (int t = lane; t < 512; t += 64) cntm += (lab[t] != -1) ? 1 : 0;
  for (int t = 1 + lane; t < 512; t += 64) {
    int tg = lab[t];
    if (tg != -1) {
      int tp = lab[t - 1];
      int tgc = min(max(tg, 0), 19);
      int tpc = min(max(tp, 0), 19);
      part += trans[tpc * 20 + tgc] + emb[t * 20 + tgc];
    }
  }
#pragma unroll
  for (int o = 32; o > 0; o >>= 1) {
    part += __shfl_xor(part, o);
    cntm += __shfl_xor(cntm, o);
  }
  if (lane == 0) {
    int t0c = min(max(lab[0], 0), 19);
    float score = startt[t0c] + emb[t0c] + part;
    int last = max(cntm - 1, 0);
    int tlc = min(max(lab[last], 0), 19);
    score += endt[tlc];
    float llh = score - logZ;
    atomicAdd(out, llh * (-1.f / 64.f));
  }
}

// ---------------------------------------------------------------------------
extern "C" void kernel_launch(void* const* d_in, const int* in_sizes, int n_in,
                              void* d_out, int out_size, void* d_ws, size_t ws_size,
                              hipStream_t stream) {
  const float* x      = (const float*)d_in[0];
  const int* labels   = (const int*)d_in[1];
  const float* Wih0   = (const float*)d_in[3];
  const float* Whh0   = (const float*)d_in[4];
  const float* bih0   = (const float*)d_in[5];
  const float* bhh0   = (const float*)d_in[6];
  const float* Wih1   = (const float*)d_in[7];
  const float* Whh1   = (const float*)d_in[8];
  const float* bih1   = (const float*)d_in[9];
  const float* bhh1   = (const float*)d_in[10];
  const float* fcw    = (const float*)d_in[11];
  const float* fcb    = (const float*)d_in[12];
  const float* startt = (const float*)d_in[13];
  const float* endt   = (const float*)d_in[14];
  const float* trans  = (const float*)d_in[15];
  float* out = (float*)d_out;

  char* ws = (char*)d_ws;
  size_t off = 0;
  auto alloc = [&](size_t bytes) -> void* {
    void* p = ws + off;
    off = (off + bytes + 255) & ~(size_t)255;
    return p;
  };
  unsigned short* h1_all = (unsigned short*)alloc(33554432ull * 2);  // 64 MB
  unsigned short* Whh0_b = (unsigned short*)alloc(4194304ull * 2);
  unsigned short* Wih0_b = (unsigned short*)alloc(2097152ull * 2);
  unsigned short* Whh1_b = (unsigned short*)alloc(4194304ull * 2);
  unsigned short* Wih1_b = (unsigned short*)alloc(4194304ull * 2);
  unsigned short* fcw_b  = (unsigned short*)alloc(20480ull * 2);
  float* bias0           = (float*)alloc(4096 * 4);
  float* bias1           = (float*)alloc(4096 * 4);
  unsigned short* h0r    = (unsigned short*)alloc(131072ull * 2);
  unsigned short* h1r    = (unsigned short*)alloc(131072ull * 2);
  float* em              = (float*)alloc(32768ull * 20 * 4);
  unsigned* flags        = (unsigned*)alloc(1024);
  unsigned* f0 = flags;
  unsigned* f1 = flags + 128;

  if (off > ws_size) {
    unsigned wsmb = (unsigned)(ws_size >> 20);
    fallback_k<<<1, 1, 0, stream>>>(out, wsmb);
    return;
  }

  hipMemsetAsync(flags, 0, 1024, stream);
  hipMemsetAsync(d_out, 0, sizeof(float), stream);

  cvt_bf16<<<4096, 256, 0, stream>>>(Whh0, Whh0_b, 4194304);
  cvt_bf16<<<2048, 256, 0, stream>>>(Wih0, Wih0_b, 2097152);
  cvt_bf16<<<4096, 256, 0, stream>>>(Whh1, Whh1_b, 4194304);
  cvt_bf16<<<4096, 256, 0, stream>>>(Wih1, Wih1_b, 4194304);
  cvt_bf16<<<20, 256, 0, stream>>>(fcw, fcw_b, 20480);
  add_vec<<<16, 256, 0, stream>>>(bih0, bhh0, bias0, 4096);
  add_vec<<<16, 256, 0, stream>>>(bih1, bhh1, bias1, 4096);

  {
    void* args[] = {(void*)&x, (void*)&Whh0_b, (void*)&Wih0_b, (void*)&Whh1_b,
                    (void*)&Wih1_b, (void*)&bias0, (void*)&bias1,
                    (void*)&h1_all, (void*)&h0r, (void*)&h1r,
                    (void*)&f0, (void*)&f1};
    hipLaunchCooperativeKernel((void*)lstm_fused, dim3(256), dim3(256), args, 0, stream);
  }
  emis_k<<<512, 256, 0, stream>>>(h1_all, fcw_b, fcb, em);
  crf_k<<<16, 256, 0, stream>>>(em, labels, startt, endt, trans, out);
}

// Round 7
// 17454.202 us; speedup vs baseline: 1.1725x; 1.0774x over previous
//
#include <hip/hip_runtime.h>
#include <hip/hip_bf16.h>
#include <hip/hip_cooperative_groups.h>
#include <stdint.h>

// ---------------------------------------------------------------------------
// 2-layer LSTM + linear + CRF NLL on MI355X.
// Round 7: TREE barrier (distributed arrival flags -> per-layer collector
// wave -> single epoch word polled by everyone). Rounds 3-6 showed ~36-44
// us/step for ALL centralized barriers regardless of data path; theory:
// poll read-storms starve arrival writes on the same IC lines. Here
// arrival-flag lines are read by exactly one collector wave, and the
// mass-polled epoch line is written by exactly one lane.
// No cache fence: ring reads are agent-scope 8-B atomic loads (IC-coherent,
// R4-proven correct; R4==R5 proved loads are not the bottleneck), so x and
// Wih stay L2-cached across steps (kills the 16 MB/step x re-fetch).
// Schedule (audited): L0 slot s: own e0>=s+1, other e1>=s; writes slab s&1.
//                     L1 slot s: own e1>=s+1, other e0>=s+2.
// Flags: f=1 after init, f=s+2 after slot s. L0 collector drains e0->513
// after its own loop so L1's last wait (e0>=513) terminates.
// ---------------------------------------------------------------------------

namespace cg = cooperative_groups;

typedef __bf16 bf16x8 __attribute__((ext_vector_type(8)));
typedef float f32x4 __attribute__((ext_vector_type(4)));

__device__ __forceinline__ f32x4 mfma16(bf16x8 a, bf16x8 b, f32x4 c) {
  return __builtin_amdgcn_mfma_f32_16x16x32_bf16(a, b, c, 0, 0, 0);
}

__device__ __forceinline__ unsigned short f2bf(float f) {
  unsigned u = __float_as_uint(f);
  u = u + 0x7fffu + ((u >> 16) & 1u);
  return (unsigned short)(u >> 16);
}
__device__ __forceinline__ float sigf(float x) { return 1.f / (1.f + __expf(-x)); }
__device__ __forceinline__ float tanh_s(float x) {
  float a = fabsf(x);
  float e = __expf(2.f * a);
  float r = 1.f - 2.f / (e + 1.f);
  return copysignf(r, x);
}
__device__ __forceinline__ bf16x8 cvt8(const float* p) {
  float4 a = *(const float4*)p;
  float4 b = *(const float4*)(p + 4);
  union { bf16x8 v; unsigned short u[8]; } r;
  r.u[0] = f2bf(a.x); r.u[1] = f2bf(a.y); r.u[2] = f2bf(a.z); r.u[3] = f2bf(a.w);
  r.u[4] = f2bf(b.x); r.u[5] = f2bf(b.y); r.u[6] = f2bf(b.z); r.u[7] = f2bf(b.w);
  return r.v;
}

// ---- agent-scope (IC-coherent) primitives ----
__device__ __forceinline__ unsigned ald32(const unsigned* p) {
  return __hip_atomic_load(p, __ATOMIC_RELAXED, __HIP_MEMORY_SCOPE_AGENT);
}
__device__ __forceinline__ unsigned long long ald64(const void* p) {
  return __hip_atomic_load((const unsigned long long*)p, __ATOMIC_RELAXED,
                           __HIP_MEMORY_SCOPE_AGENT);
}
__device__ __forceinline__ void ast32(void* p, unsigned v) {
  __hip_atomic_store((unsigned*)p, v, __ATOMIC_RELAXED, __HIP_MEMORY_SCOPE_AGENT);
}
__device__ __forceinline__ void ast64(void* p, unsigned long long v) {
  __hip_atomic_store((unsigned long long*)p, v, __ATOMIC_RELAXED,
                     __HIP_MEMORY_SCOPE_AGENT);
}
__device__ __forceinline__ bf16x8 ldh(const unsigned short* p) {  // 16B via 2x8B IC loads
  union { bf16x8 v; unsigned long long q[2]; } u;
  u.q[0] = ald64(p);
  u.q[1] = ald64(p + 4);
  return u.v;
}

// ---------------------------------------------------------------------------
__global__ void fallback_k(float* out, unsigned wsmb) { *out = -(float)wsmb; }

__global__ void cvt_bf16(const float* __restrict__ in, unsigned short* __restrict__ out, int n) {
  int i = (blockIdx.x * 256 + threadIdx.x) * 4;
  if (i < n) {
    float4 v = *(const float4*)(in + i);
    ushort4 o;
    o.x = f2bf(v.x); o.y = f2bf(v.y); o.z = f2bf(v.z); o.w = f2bf(v.w);
    *(ushort4*)(out + i) = o;
  }
}

__global__ void add_vec(const float* __restrict__ a, const float* __restrict__ b,
                        float* __restrict__ o, int n) {
  int i = blockIdx.x * 256 + threadIdx.x;
  if (i < n) o[i] = a[i] + b[i];
}

// ---------------------------------------------------------------------------
// Fused 2-layer persistent scan, tree barrier.
// MFMA roles: A = W rows (m = jj*4 + gate -> lane holds all 4 gates of one
// (batch, hidden) pair in D regs), B = h / x.
#define BS(mi, ks) (*(const bf16x8*)&Bsm[(((mi)*2048 + (ks)*64 + lane)) * 8])

__global__ __launch_bounds__(256, 1) void lstm_fused(
    const float* __restrict__ x,              // [64][512][512] fp32
    const unsigned short* __restrict__ Whh0b, const unsigned short* __restrict__ Wih0b,
    const unsigned short* __restrict__ Whh1b, const unsigned short* __restrict__ Wih1b,
    const float* __restrict__ bias0, const float* __restrict__ bias1,
    unsigned short* __restrict__ h1_all,      // [64][512][1024] bf16
    unsigned short* h0r, unsigned short* h1r, // [2][64][1024] rings
    unsigned* flags)   // [0..127]=f0, [128..255]=f1, [256]=e0, [257]=e1
{
  __shared__ __align__(16) unsigned short Bsm[32768];   // 64 KB Whh A-frags
  const int tid = threadIdx.x;
  const int lane = tid & 63;
  const int w = tid >> 6;            // wave = 16-batch tile
  const int c16 = lane & 15, rg = lane >> 4;
  const bool is1 = blockIdx.x >= 128;
  const int bid = is1 ? (int)blockIdx.x - 128 : (int)blockIdx.x;
  const int j0 = bid * 8;
  unsigned* fown = flags + (is1 ? 128 : 0);
  unsigned* ep   = flags + 256;               // epoch pair {e0,e1}, one line
  const bool collector = (bid == 0);

  // ---- LDS: Whh A-frags. unit u = mi*2048 + ks*64 + ln; ln is the MFMA lane:
  // m=ln&15 -> (gate=m&3, jj=m>>2); k = ks*32 + (ln>>4)*8.
  {
    const unsigned short* W = is1 ? Whh1b : Whh0b;
    for (int u = tid; u < 4096; u += 256) {
      int mi = u >> 11;
      int ks = (u >> 6) & 31;
      int ln = u & 63;
      int m = ln & 15;
      long row = (long)(m & 3) * 1024 + j0 + mi * 4 + (m >> 2);
      *(bf16x8*)&Bsm[u * 8] = *(const bf16x8*)(W + row * 1024 + ks * 32 + (ln >> 4) * 8);
    }
  }
  // ---- Registers/L2: Wih A-frags (compiler may reload; L2-resident, no inv) --
  bf16x8 wf[2][32];
  {
    const int g = c16 & 3, jj = c16 >> 2;
    if (is1) {
#pragma unroll
      for (int mi = 0; mi < 2; ++mi) {
        long row = (long)g * 1024 + j0 + mi * 4 + jj;
#pragma unroll
        for (int ks = 0; ks < 32; ++ks)
          wf[mi][ks] = *(const bf16x8*)(Wih1b + row * 1024 + ks * 32 + rg * 8);
      }
    } else {
#pragma unroll
      for (int mi = 0; mi < 2; ++mi) {
        long row = (long)g * 1024 + j0 + mi * 4 + jj;
#pragma unroll
        for (int ks = 0; ks < 16; ++ks)
          wf[mi][ks] = *(const bf16x8*)(Wih0b + row * 512 + ks * 32 + rg * 8);
      }
    }
  }
  // ---- biases ----
  const float* bias = is1 ? bias1 : bias0;
  float bs[2][4];
#pragma unroll
  for (int mi = 0; mi < 2; ++mi)
#pragma unroll
    for (int r = 0; r < 4; ++r) bs[mi][r] = bias[r * 1024 + j0 + mi * 4 + rg];

  // ---- zero own slice of slab 1 of own ring (read as h[-1]) ----
  unsigned short* ring = is1 ? h1r : h0r;
  if (tid < 128) ast64(ring + 65536 + (tid >> 1) * 1024 + j0 + (tid & 1) * 4, 0ull);
  __syncthreads();                        // drains vmcnt for all waves
  if (tid == 0) ast32(fown + bid, 1u);    // init arrival

  const int boff = (w * 16 + c16) * 1024;
  const int koffbase = rg * 8;
  float cst[2] = {0.f, 0.f};
  const f32x4 fz = {0.f, 0.f, 0.f, 0.f};

  for (int s = 0; s < 512; ++s) {
    // L0: prefetch x frags (barrier-independent, L2-cached)
    bf16x8 xa[16];
    if (!is1) {
      const float* xp = x + ((long)(w * 16 + c16) * 512 + s) * 512 + koffbase;
#pragma unroll
      for (int ks = 0; ks < 16; ++ks) xa[ks] = cvt8(xp + ks * 32);
    }
    // ---- wait (tree barrier) ----
    const unsigned t_own = (unsigned)(s + 1);
    const unsigned t_oth = (unsigned)(is1 ? s + 2 : s);
    if (collector) {
      if (tid < 64) {
        for (;;) {
          unsigned a = ald32(fown + lane);
          unsigned b = ald32(fown + lane + 64);
          unsigned mn = a < b ? a : b;
#pragma unroll
          for (int o = 32; o > 0; o >>= 1) {
            unsigned t = (unsigned)__shfl_xor((int)mn, o);
            mn = t < mn ? t : mn;
          }
          if (lane == 0) ast32(ep + (is1 ? 1 : 0), mn);   // publish epoch
          unsigned eo = ald32(ep + (is1 ? 0 : 1));        // same addr all lanes
          if (mn >= t_own && eo >= t_oth) break;
          __builtin_amdgcn_s_sleep(1);
        }
      }
    } else {
      if (tid < 64) {
        for (;;) {
          unsigned long long v = ald64(ep);               // same addr all lanes
          unsigned e0v = (unsigned)v, e1v = (unsigned)(v >> 32);
          unsigned eov = is1 ? e1v : e0v;
          unsigned eot = is1 ? e0v : e1v;
          if (eov >= t_own && eot >= t_oth) break;
          __builtin_amdgcn_s_sleep(4);
        }
      }
    }
    __syncthreads();
    __atomic_signal_fence(__ATOMIC_ACQ_REL);   // compiler reorder guard

    f32x4 aW0 = fz, aW1 = fz, aI0 = fz, aI1 = fz;
    const unsigned short* hprev = ring + ((s + 1) & 1) * 65536 + boff + koffbase;
    if (!is1) {
#pragma unroll 8
      for (int ks = 0; ks < 32; ++ks) {
        bf16x8 hb = ldh(hprev + ks * 32);
        aW0 = mfma16(BS(0, ks), hb, aW0);
        aW1 = mfma16(BS(1, ks), hb, aW1);
      }
#pragma unroll
      for (int ks = 0; ks < 16; ++ks) {
        aI0 = mfma16(wf[0][ks], xa[ks], aI0);
        aI1 = mfma16(wf[1][ks], xa[ks], aI1);
      }
    } else {
      const unsigned short* h0p = h0r + (s & 1) * 65536 + boff + koffbase;
#pragma unroll 8
      for (int ks = 0; ks < 32; ++ks) {
        bf16x8 hb = ldh(hprev + ks * 32);
        bf16x8 h0b = ldh(h0p + ks * 32);
        aW0 = mfma16(BS(0, ks), hb, aW0);
        aW1 = mfma16(BS(1, ks), hb, aW1);
        aI0 = mfma16(wf[0][ks], h0b, aI0);
        aI1 = mfma16(wf[1][ks], h0b, aI1);
      }
    }
    // ---- gates (lane-local), cell update, packed 32-bit write-through store ----
    unsigned short* rout = ring + (s & 1) * 65536;
    const int b = w * 16 + c16;
#pragma unroll
    for (int mi = 0; mi < 2; ++mi) {
      float p_i = (mi ? aW1[0] + aI1[0] : aW0[0] + aI0[0]) + bs[mi][0];
      float p_f = (mi ? aW1[1] + aI1[1] : aW0[1] + aI0[1]) + bs[mi][1];
      float p_g = (mi ? aW1[2] + aI1[2] : aW0[2] + aI0[2]) + bs[mi][2];
      float p_o = (mi ? aW1[3] + aI1[3] : aW0[3] + aI0[3]) + bs[mi][3];
      float iv = sigf(p_i);
      float fv = sigf(p_f);
      float gv = tanh_s(p_g);
      float ov = sigf(p_o);
      float cn = fv * cst[mi] + iv * gv;
      cst[mi] = cn;
      float hv = ov * tanh_s(cn);
      unsigned hu = f2bf(hv);
      int j = j0 + mi * 4 + rg;
      unsigned pu = (unsigned)__shfl_xor((int)hu, 16);
      if ((rg & 1) == 0) ast32(rout + b * 1024 + j, hu | (pu << 16));
      if (is1) h1_all[((long)b * 512 + s) * 1024 + j] = (unsigned short)hu;
    }
    __syncthreads();                                  // drain ring stores
    if (tid == 0) ast32(fown + bid, (unsigned)(s + 2));  // arrival
  }
  // ---- L0 collector drains e0 to 513 so L1's final wait terminates ----
  if (!is1 && collector && tid < 64) {
    for (;;) {
      unsigned a = ald32(fown + lane);
      unsigned b = ald32(fown + lane + 64);
      unsigned mn = a < b ? a : b;
#pragma unroll
      for (int o = 32; o > 0; o >>= 1) {
        unsigned t = (unsigned)__shfl_xor((int)mn, o);
        mn = t < mn ? t : mn;
      }
      if (lane == 0) ast32(ep, mn);
      if (mn >= 513u) break;
      __builtin_amdgcn_s_sleep(1);
    }
  }
}

// ---------------------------------------------------------------------------
// emissions[m][c] = h1[m][:] . fc_w[c][:] + fc_b[c], c<20 (N padded to 32).
__global__ __launch_bounds__(256) void emis_k(
    const unsigned short* __restrict__ h1, const unsigned short* __restrict__ fcw,
    const float* __restrict__ fcb, float* __restrict__ em) {
  __shared__ __align__(16) unsigned short Bsm[32768];
  const int tid = threadIdx.x;
  const int lane = tid & 63;
  const int w = tid >> 6;
  const int c16 = lane & 15, rg = lane >> 4;
  for (int u = tid; u < 4096; u += 256) {
    int tile = u >> 11;
    int ks = (u >> 6) & 31;
    int ln = u & 63;
    int n = tile * 16 + (ln & 15);
    int kb = ks * 32 + (ln >> 4) * 8;
    if (n < 20) {
      *(bf16x8*)&Bsm[u * 8] = *(const bf16x8*)(fcw + (long)n * 1024 + kb);
    } else {
#pragma unroll
      for (int j = 0; j < 8; ++j) Bsm[u * 8 + j] = 0;
    }
  }
  __syncthreads();
  const long r0 = (long)blockIdx.x * 64;
  const bf16x8* arow = (const bf16x8*)(h1 + (r0 + w * 16 + c16) * 1024 + rg * 8);
  const f32x4 fz = {0.f, 0.f, 0.f, 0.f};
  f32x4 acc0 = fz, acc1 = fz;
#pragma unroll 4
  for (int ks = 0; ks < 32; ++ks) {
    bf16x8 a = arow[ks * 4];
    acc0 = mfma16(a, *(const bf16x8*)&Bsm[(ks * 64 + lane) * 8], acc0);
    acc1 = mfma16(a, *(const bf16x8*)&Bsm[((32 + ks) * 64 + lane) * 8], acc1);
  }
#pragma unroll
  for (int r = 0; r < 4; ++r) {
    long row = r0 + w * 16 + rg * 4 + r;
    em[row * 20 + c16] = acc0[r] + fcb[c16];
    int col1 = 16 + c16;
    if (col1 < 20) em[row * 20 + col1] = acc1[r] + fcb[col1];
  }
}

// ---------------------------------------------------------------------------
// CRF NLL: one wave per batch. Lanes 0..19 hold alpha[j]; 511 serial steps.
__global__ __launch_bounds__(256) void crf_k(
    const float* __restrict__ em, const int* __restrict__ labels,
    const float* __restrict__ startt, const float* __restrict__ endt,
    const float* __restrict__ trans, float* __restrict__ out) {
  const int lane = threadIdx.x & 63;
  const int b = blockIdx.x * 4 + (threadIdx.x >> 6);
  const float NEG = -1e30f;
  const int j = lane;
  const bool act = j < 20;
  float treg[20];
#pragma unroll
  for (int i = 0; i < 20; ++i) treg[i] = act ? trans[i * 20 + j] : 0.f;
  const float* emb = em + (long)b * 512 * 20;
  const int* lab = labels + (long)b * 512;
  float alpha = act ? (startt[j] + emb[j]) : NEG;
  for (int t = 1; t < 512; ++t) {
    float mx = NEG;
#pragma unroll
    for (int i = 0; i < 20; ++i) {
      float v = __shfl(alpha, i) + treg[i];
      mx = fmaxf(mx, v);
    }
    float s = 0.f;
#pragma unroll
    for (int i = 0; i < 20; ++i) {
      float v = __shfl(alpha, i) + treg[i];
      s += __expf(v - mx);
    }
    bool m = lab[t] != -1;
    float na = emb[t * 20 + (act ? j : 0)] + mx + __logf(s);
    if (act && m) alpha = na;
  }
  float v = act ? (alpha + endt[j]) : NEG;
  float mx = v;
#pragma unroll
  for (int o = 32; o > 0; o >>= 1) mx = fmaxf(mx, __shfl_xor(mx, o));
  float s = act ? __expf(v - mx) : 0.f;
#pragma unroll
  for (int o = 32; o > 0; o >>= 1) s += __shfl_xor(s, o);
  float logZ = mx + __logf(s);
  float part = 0.f;
  int cntm = 0;
  for (int t = lane; t < 512; t += 64) cntm += (lab[t] != -1) ? 1 : 0;
  for (int t = 1 + lane; t < 512; t += 64) {
    int tg = lab[t];
    if (tg != -1) {
      int tp = lab[t - 1];
      int tgc = min(max(tg, 0), 19);
      int tpc = min(max(tp, 0), 19);
      part += trans[tpc * 20 + tgc] + emb[t * 20 + tgc];
    }
  }
#pragma unroll
  for (int o = 32; o > 0; o >>= 1) {
    part += __shfl_xor(part, o);
    cntm += __shfl_xor(cntm, o);
  }
  if (lane == 0) {
    int t0c = min(max(lab[0], 0), 19);
    float score = startt[t0c] + emb[t0c] + part;
    int last = max(cntm - 1, 0);
    int tlc = min(max(lab[last], 0), 19);
    score += endt[tlc];
    float llh = score - logZ;
    atomicAdd(out, llh * (-1.f / 64.f));
  }
}

// ---------------------------------------------------------------------------
extern "C" void kernel_launch(void* const* d_in, const int* in_sizes, int n_in,
                              void* d_out, int out_size, void* d_ws, size_t ws_size,
                              hipStream_t stream) {
  const float* x      = (const float*)d_in[0];
  const int* labels   = (const int*)d_in[1];
  const float* Wih0   = (const float*)d_in[3];
  const float* Whh0   = (const float*)d_in[4];
  const float* bih0   = (const float*)d_in[5];
  const float* bhh0   = (const float*)d_in[6];
  const float* Wih1   = (const float*)d_in[7];
  const float* Whh1   = (const float*)d_in[8];
  const float* bih1   = (const float*)d_in[9];
  const float* bhh1   = (const float*)d_in[10];
  const float* fcw    = (const float*)d_in[11];
  const float* fcb    = (const float*)d_in[12];
  const float* startt = (const float*)d_in[13];
  const float* endt   = (const float*)d_in[14];
  const float* trans  = (const float*)d_in[15];
  float* out = (float*)d_out;

  char* ws = (char*)d_ws;
  size_t off = 0;
  auto alloc = [&](size_t bytes) -> void* {
    void* p = ws + off;
    off = (off + bytes + 255) & ~(size_t)255;
    return p;
  };
  unsigned short* h1_all = (unsigned short*)alloc(33554432ull * 2);  // 64 MB
  unsigned short* Whh0_b = (unsigned short*)alloc(4194304ull * 2);
  unsigned short* Wih0_b = (unsigned short*)alloc(2097152ull * 2);
  unsigned short* Whh1_b = (unsigned short*)alloc(4194304ull * 2);
  unsigned short* Wih1_b = (unsigned short*)alloc(4194304ull * 2);
  unsigned short* fcw_b  = (unsigned short*)alloc(20480ull * 2);
  float* bias0           = (float*)alloc(4096 * 4);
  float* bias1           = (float*)alloc(4096 * 4);
  unsigned short* h0r    = (unsigned short*)alloc(131072ull * 2);
  unsigned short* h1r    = (unsigned short*)alloc(131072ull * 2);
  float* em              = (float*)alloc(32768ull * 20 * 4);
  unsigned* flags        = (unsigned*)alloc(2048);

  if (off > ws_size) {
    unsigned wsmb = (unsigned)(ws_size >> 20);
    fallback_k<<<1, 1, 0, stream>>>(out, wsmb);
    return;
  }

  hipMemsetAsync(flags, 0, 2048, stream);
  hipMemsetAsync(d_out, 0, sizeof(float), stream);

  cvt_bf16<<<4096, 256, 0, stream>>>(Whh0, Whh0_b, 4194304);
  cvt_bf16<<<2048, 256, 0, stream>>>(Wih0, Wih0_b, 2097152);
  cvt_bf16<<<4096, 256, 0, stream>>>(Whh1, Whh1_b, 4194304);
  cvt_bf16<<<4096, 256, 0, stream>>>(Wih1, Wih1_b, 4194304);
  cvt_bf16<<<20, 256, 0, stream>>>(fcw, fcw_b, 20480);
  add_vec<<<16, 256, 0, stream>>>(bih0, bhh0, bias0, 4096);
  add_vec<<<16, 256, 0, stream>>>(bih1, bhh1, bias1, 4096);

  {
    void* args[] = {(void*)&x, (void*)&Whh0_b, (void*)&Wih0_b, (void*)&Whh1_b,
                    (void*)&Wih1_b, (void*)&bias0, (void*)&bias1,
                    (void*)&h1_all, (void*)&h0r, (void*)&h1r, (void*)&flags};
    hipLaunchCooperativeKernel((void*)lstm_fused, dim3(256), dim3(256), args, 0, stream);
  }
  emis_k<<<512, 256, 0, stream>>>(h1_all, fcw_b, fcb, em);
  crf_k<<<16, 256, 0, stream>>>(em, labels, startt, endt, trans, out);
}

// Round 8
// 9425.066 us; speedup vs baseline: 2.1713x; 1.8519x over previous
//
#include <hip/hip_runtime.h>
#include <hip/hip_bf16.h>
#include <hip/hip_cooperative_groups.h>
#include <stdint.h>

// ---------------------------------------------------------------------------
// 2-layer LSTM + linear + CRF NLL on MI355X.
// Round 8: Wih fragments move to LDS (dynamic 128 KB: 64 KB Whh + 64 KB Wih).
// R4-R7 post-mortem: VGPR_Count=136 proved wf[2][32] (256 VGPRs) never fit in
// registers -> compiler re-loaded Wih from global EVERY step (48 MB/step,
// 6 MB/step/XCD -> L2 thrash -> x never cached either). FETCH 8.4 GB at
// latency-limited ~540 GB/s == the entire 17 ms. Barriers were never the
// bottleneck (4 variants, same time). Keep R7 tree barrier + atomic ring IO.
// ---------------------------------------------------------------------------

namespace cg = cooperative_groups;

typedef __bf16 bf16x8 __attribute__((ext_vector_type(8)));
typedef float f32x4 __attribute__((ext_vector_type(4)));

__device__ __forceinline__ f32x4 mfma16(bf16x8 a, bf16x8 b, f32x4 c) {
  return __builtin_amdgcn_mfma_f32_16x16x32_bf16(a, b, c, 0, 0, 0);
}

__device__ __forceinline__ unsigned short f2bf(float f) {
  unsigned u = __float_as_uint(f);
  u = u + 0x7fffu + ((u >> 16) & 1u);
  return (unsigned short)(u >> 16);
}
__device__ __forceinline__ float sigf(float x) { return 1.f / (1.f + __expf(-x)); }
__device__ __forceinline__ float tanh_s(float x) {
  float a = fabsf(x);
  float e = __expf(2.f * a);
  float r = 1.f - 2.f / (e + 1.f);
  return copysignf(r, x);
}
__device__ __forceinline__ bf16x8 cvt8(const float* p) {
  float4 a = *(const float4*)p;
  float4 b = *(const float4*)(p + 4);
  union { bf16x8 v; unsigned short u[8]; } r;
  r.u[0] = f2bf(a.x); r.u[1] = f2bf(a.y); r.u[2] = f2bf(a.z); r.u[3] = f2bf(a.w);
  r.u[4] = f2bf(b.x); r.u[5] = f2bf(b.y); r.u[6] = f2bf(b.z); r.u[7] = f2bf(b.w);
  return r.v;
}

// ---- agent-scope (IC-coherent) primitives ----
__device__ __forceinline__ unsigned ald32(const unsigned* p) {
  return __hip_atomic_load(p, __ATOMIC_RELAXED, __HIP_MEMORY_SCOPE_AGENT);
}
__device__ __forceinline__ unsigned long long ald64(const void* p) {
  return __hip_atomic_load((const unsigned long long*)p, __ATOMIC_RELAXED,
                           __HIP_MEMORY_SCOPE_AGENT);
}
__device__ __forceinline__ void ast32(void* p, unsigned v) {
  __hip_atomic_store((unsigned*)p, v, __ATOMIC_RELAXED, __HIP_MEMORY_SCOPE_AGENT);
}
__device__ __forceinline__ void ast64(void* p, unsigned long long v) {
  __hip_atomic_store((unsigned long long*)p, v, __ATOMIC_RELAXED,
                     __HIP_MEMORY_SCOPE_AGENT);
}
__device__ __forceinline__ bf16x8 ldh(const unsigned short* p) {  // 16B via 2x8B IC loads
  union { bf16x8 v; unsigned long long q[2]; } u;
  u.q[0] = ald64(p);
  u.q[1] = ald64(p + 4);
  return u.v;
}

// ---------------------------------------------------------------------------
__global__ void fallback_k(float* out, unsigned wsmb) { *out = -(float)wsmb; }

__global__ void cvt_bf16(const float* __restrict__ in, unsigned short* __restrict__ out, int n) {
  int i = (blockIdx.x * 256 + threadIdx.x) * 4;
  if (i < n) {
    float4 v = *(const float4*)(in + i);
    ushort4 o;
    o.x = f2bf(v.x); o.y = f2bf(v.y); o.z = f2bf(v.z); o.w = f2bf(v.w);
    *(ushort4*)(out + i) = o;
  }
}

__global__ void add_vec(const float* __restrict__ a, const float* __restrict__ b,
                        float* __restrict__ o, int n) {
  int i = blockIdx.x * 256 + threadIdx.x;
  if (i < n) o[i] = a[i] + b[i];
}

// ---------------------------------------------------------------------------
// Fused 2-layer persistent scan, tree barrier, ALL weight fragments in LDS.
// MFMA roles: A = W rows (m = jj*4 + gate -> lane holds all 4 gates of one
// (batch, hidden) pair in D regs), B = h / x.
// Dynamic LDS layout (unsigned short units):
//   [0       .. 32768)  Whh frags: (mi*2048 + ks*64 + lane)*8,  ks in [0,32)
//   [32768   ..  end )  Wih frags: L0 (mi*1024+ks*64+lane)*8 ks<16 (32 KB)
//                                  L1 (mi*2048+ks*64+lane)*8 ks<32 (64 KB)
#define BS(mi, ks)  (*(const bf16x8*)&Bsm[(((mi)*2048 + (ks)*64 + lane)) * 8])
#define WS0(mi, ks) (*(const bf16x8*)&Bsm[32768 + (((mi)*1024 + (ks)*64 + lane)) * 8])
#define WS1(mi, ks) (*(const bf16x8*)&Bsm[32768 + (((mi)*2048 + (ks)*64 + lane)) * 8])

__global__ __launch_bounds__(256, 1) void lstm_fused(
    const float* __restrict__ x,              // [64][512][512] fp32
    const unsigned short* __restrict__ Whh0b, const unsigned short* __restrict__ Wih0b,
    const unsigned short* __restrict__ Whh1b, const unsigned short* __restrict__ Wih1b,
    const float* __restrict__ bias0, const float* __restrict__ bias1,
    unsigned short* __restrict__ h1_all,      // [64][512][1024] bf16
    unsigned short* h0r, unsigned short* h1r, // [2][64][1024] rings
    unsigned* flags)   // [0..127]=f0, [128..255]=f1, [256]=e0, [257]=e1
{
  extern __shared__ __align__(16) unsigned short Bsm[];
  const int tid = threadIdx.x;
  const int lane = tid & 63;
  const int w = tid >> 6;            // wave = 16-batch tile
  const int c16 = lane & 15, rg = lane >> 4;
  const bool is1 = blockIdx.x >= 128;
  const int bid = is1 ? (int)blockIdx.x - 128 : (int)blockIdx.x;
  const int j0 = bid * 8;
  unsigned* fown = flags + (is1 ? 128 : 0);
  unsigned* ep   = flags + 256;               // epoch pair {e0,e1}, one line
  const bool collector = (bid == 0);

  // ---- LDS: Whh A-frags. unit u = mi*2048 + ks*64 + ln; ln is the MFMA lane:
  // m=ln&15 -> (gate=m&3, jj=m>>2); k = ks*32 + (ln>>4)*8.
  {
    const unsigned short* W = is1 ? Whh1b : Whh0b;
    for (int u = tid; u < 4096; u += 256) {
      int mi = u >> 11;
      int ks = (u >> 6) & 31;
      int ln = u & 63;
      int m = ln & 15;
      long row = (long)(m & 3) * 1024 + j0 + mi * 4 + (m >> 2);
      *(bf16x8*)&Bsm[u * 8] = *(const bf16x8*)(W + row * 1024 + ks * 32 + (ln >> 4) * 8);
    }
  }
  // ---- LDS: Wih A-frags (same fragment scheme; K=512 for L0, K=1024 for L1) --
  if (is1) {
    for (int u = tid; u < 4096; u += 256) {
      int mi = u >> 11;
      int ks = (u >> 6) & 31;
      int ln = u & 63;
      int m = ln & 15;
      long row = (long)(m & 3) * 1024 + j0 + mi * 4 + (m >> 2);
      *(bf16x8*)&Bsm[32768 + u * 8] =
          *(const bf16x8*)(Wih1b + row * 1024 + ks * 32 + (ln >> 4) * 8);
    }
  } else {
    for (int u = tid; u < 2048; u += 256) {
      int mi = u >> 10;
      int ks = (u >> 6) & 15;
      int ln = u & 63;
      int m = ln & 15;
      long row = (long)(m & 3) * 1024 + j0 + mi * 4 + (m >> 2);
      *(bf16x8*)&Bsm[32768 + u * 8] =
          *(const bf16x8*)(Wih0b + row * 512 + ks * 32 + (ln >> 4) * 8);
    }
  }
  // ---- biases ----
  const float* bias = is1 ? bias1 : bias0;
  float bs[2][4];
#pragma unroll
  for (int mi = 0; mi < 2; ++mi)
#pragma unroll
    for (int r = 0; r < 4; ++r) bs[mi][r] = bias[r * 1024 + j0 + mi * 4 + rg];

  // ---- zero own slice of slab 1 of own ring (read as h[-1]) ----
  unsigned short* ring = is1 ? h1r : h0r;
  if (tid < 128) ast64(ring + 65536 + (tid >> 1) * 1024 + j0 + (tid & 1) * 4, 0ull);
  __syncthreads();                        // drains vmcnt for all waves
  if (tid == 0) ast32(fown + bid, 1u);    // init arrival

  const int boff = (w * 16 + c16) * 1024;
  const int koffbase = rg * 8;
  float cst[2] = {0.f, 0.f};
  const f32x4 fz = {0.f, 0.f, 0.f, 0.f};

  for (int s = 0; s < 512; ++s) {
    // L0: prefetch x frags (barrier-independent; slab identical across L0
    // blocks -> L2-shared now that weight thrash is gone)
    bf16x8 xa[16];
    if (!is1) {
      const float* xp = x + ((long)(w * 16 + c16) * 512 + s) * 512 + koffbase;
#pragma unroll
      for (int ks = 0; ks < 16; ++ks) xa[ks] = cvt8(xp + ks * 32);
    }
    // ---- wait (tree barrier) ----
    const unsigned t_own = (unsigned)(s + 1);
    const unsigned t_oth = (unsigned)(is1 ? s + 2 : s);
    if (collector) {
      if (tid < 64) {
        for (;;) {
          unsigned a = ald32(fown + lane);
          unsigned b = ald32(fown + lane + 64);
          unsigned mn = a < b ? a : b;
#pragma unroll
          for (int o = 32; o > 0; o >>= 1) {
            unsigned t = (unsigned)__shfl_xor((int)mn, o);
            mn = t < mn ? t : mn;
          }
          if (lane == 0) ast32(ep + (is1 ? 1 : 0), mn);   // publish epoch
          unsigned eo = ald32(ep + (is1 ? 0 : 1));        // same addr all lanes
          if (mn >= t_own && eo >= t_oth) break;
          __builtin_amdgcn_s_sleep(1);
        }
      }
    } else {
      if (tid < 64) {
        for (;;) {
          unsigned long long v = ald64(ep);               // same addr all lanes
          unsigned e0v = (unsigned)v, e1v = (unsigned)(v >> 32);
          unsigned eov = is1 ? e1v : e0v;
          unsigned eot = is1 ? e0v : e1v;
          if (eov >= t_own && eot >= t_oth) break;
          __builtin_amdgcn_s_sleep(4);
        }
      }
    }
    __syncthreads();
    __atomic_signal_fence(__ATOMIC_ACQ_REL);   // compiler reorder guard

    f32x4 aW0 = fz, aW1 = fz, aI0 = fz, aI1 = fz;
    const unsigned short* hprev = ring + ((s + 1) & 1) * 65536 + boff + koffbase;
    if (!is1) {
#pragma unroll 8
      for (int ks = 0; ks < 32; ++ks) {
        bf16x8 hb = ldh(hprev + ks * 32);
        aW0 = mfma16(BS(0, ks), hb, aW0);
        aW1 = mfma16(BS(1, ks), hb, aW1);
      }
#pragma unroll
      for (int ks = 0; ks < 16; ++ks) {
        aI0 = mfma16(WS0(0, ks), xa[ks], aI0);
        aI1 = mfma16(WS0(1, ks), xa[ks], aI1);
      }
    } else {
      const unsigned short* h0p = h0r + (s & 1) * 65536 + boff + koffbase;
#pragma unroll 8
      for (int ks = 0; ks < 32; ++ks) {
        bf16x8 hb = ldh(hprev + ks * 32);
        bf16x8 h0b = ldh(h0p + ks * 32);
        aW0 = mfma16(BS(0, ks), hb, aW0);
        aW1 = mfma16(BS(1, ks), hb, aW1);
        aI0 = mfma16(WS1(0, ks), h0b, aI0);
        aI1 = mfma16(WS1(1, ks), h0b, aI1);
      }
    }
    // ---- gates (lane-local), cell update, packed 32-bit write-through store ----
    unsigned short* rout = ring + (s & 1) * 65536;
    const int b = w * 16 + c16;
#pragma unroll
    for (int mi = 0; mi < 2; ++mi) {
      float p_i = (mi ? aW1[0] + aI1[0] : aW0[0] + aI0[0]) + bs[mi][0];
      float p_f = (mi ? aW1[1] + aI1[1] : aW0[1] + aI0[1]) + bs[mi][1];
      float p_g = (mi ? aW1[2] + aI1[2] : aW0[2] + aI0[2]) + bs[mi][2];
      float p_o = (mi ? aW1[3] + aI1[3] : aW0[3] + aI0[3]) + bs[mi][3];
      float iv = sigf(p_i);
      float fv = sigf(p_f);
      float gv = tanh_s(p_g);
      float ov = sigf(p_o);
      float cn = fv * cst[mi] + iv * gv;
      cst[mi] = cn;
      float hv = ov * tanh_s(cn);
      unsigned hu = f2bf(hv);
      int j = j0 + mi * 4 + rg;
      unsigned pu = (unsigned)__shfl_xor((int)hu, 16);
      if ((rg & 1) == 0) ast32(rout + b * 1024 + j, hu | (pu << 16));
      if (is1) h1_all[((long)b * 512 + s) * 1024 + j] = (unsigned short)hu;
    }
    __syncthreads();                                  // drain ring stores
    if (tid == 0) ast32(fown + bid, (unsigned)(s + 2));  // arrival
  }
  // ---- L0 collector drains e0 to 513 so L1's final wait terminates ----
  if (!is1 && collector && tid < 64) {
    for (;;) {
      unsigned a = ald32(fown + lane);
      unsigned b = ald32(fown + lane + 64);
      unsigned mn = a < b ? a : b;
#pragma unroll
      for (int o = 32; o > 0; o >>= 1) {
        unsigned t = (unsigned)__shfl_xor((int)mn, o);
        mn = t < mn ? t : mn;
      }
      if (lane == 0) ast32(ep, mn);
      if (mn >= 513u) break;
      __builtin_amdgcn_s_sleep(1);
    }
  }
}

// ---------------------------------------------------------------------------
// emissions[m][c] = h1[m][:] . fc_w[c][:] + fc_b[c], c<20 (N padded to 32).
__global__ __launch_bounds__(256) void emis_k(
    const unsigned short* __restrict__ h1, const unsigned short* __restrict__ fcw,
    const float* __restrict__ fcb, float* __restrict__ em) {
  __shared__ __align__(16) unsigned short Bsm[32768];
  const int tid = threadIdx.x;
  const int lane = tid & 63;
  const int w = tid >> 6;
  const int c16 = lane & 15, rg = lane >> 4;
  for (int u = tid; u < 4096; u += 256) {
    int tile = u >> 11;
    int ks = (u >> 6) & 31;
    int ln = u & 63;
    int n = tile * 16 + (ln & 15);
    int kb = ks * 32 + (ln >> 4) * 8;
    if (n < 20) {
      *(bf16x8*)&Bsm[u * 8] = *(const bf16x8*)(fcw + (long)n * 1024 + kb);
    } else {
#pragma unroll
      for (int j = 0; j < 8; ++j) Bsm[u * 8 + j] = 0;
    }
  }
  __syncthreads();
  const long r0 = (long)blockIdx.x * 64;
  const bf16x8* arow = (const bf16x8*)(h1 + (r0 + w * 16 + c16) * 1024 + rg * 8);
  const f32x4 fz = {0.f, 0.f, 0.f, 0.f};
  f32x4 acc0 = fz, acc1 = fz;
#pragma unroll 4
  for (int ks = 0; ks < 32; ++ks) {
    bf16x8 a = arow[ks * 4];
    acc0 = mfma16(a, *(const bf16x8*)&Bsm[(ks * 64 + lane) * 8], acc0);
    acc1 = mfma16(a, *(const bf16x8*)&Bsm[((32 + ks) * 64 + lane) * 8], acc1);
  }
#pragma unroll
  for (int r = 0; r < 4; ++r) {
    long row = r0 + w * 16 + rg * 4 + r;
    em[row * 20 + c16] = acc0[r] + fcb[c16];
    int col1 = 16 + c16;
    if (col1 < 20) em[row * 20 + col1] = acc1[r] + fcb[col1];
  }
}

// ---------------------------------------------------------------------------
// CRF NLL: one wave per batch. Lanes 0..19 hold alpha[j]; 511 serial steps.
__global__ __launch_bounds__(256) void crf_k(
    const float* __restrict__ em, const int* __restrict__ labels,
    const float* __restrict__ startt, const float* __restrict__ endt,
    const float* __restrict__ trans, float* __restrict__ out) {
  const int lane = threadIdx.x & 63;
  const int b = blockIdx.x * 4 + (threadIdx.x >> 6);
  const float NEG = -1e30f;
  const int j = lane;
  const bool act = j < 20;
  float treg[20];
#pragma unroll
  for (int i = 0; i < 20; ++i) treg[i] = act ? trans[i * 20 + j] : 0.f;
  const float* emb = em + (long)b * 512 * 20;
  const int* lab = labels + (long)b * 512;
  float alpha = act ? (startt[j] + emb[j]) : NEG;
  for (int t = 1; t < 512; ++t) {
    float mx = NEG;
#pragma unroll
    for (int i = 0; i < 20; ++i) {
      float v = __shfl(alpha, i) + treg[i];
      mx = fmaxf(mx, v);
    }
    float s = 0.f;
#pragma unroll
    for (int i = 0; i < 20; ++i) {
      float v = __shfl(alpha, i) + treg[i];
      s += __expf(v - mx);
    }
    bool m = lab[t] != -1;
    float na = emb[t * 20 + (act ? j : 0)] + mx + __logf(s);
    if (act && m) alpha = na;
  }
  float v = act ? (alpha + endt[j]) : NEG;
  float mx = v;
#pragma unroll
  for (int o = 32; o > 0; o >>= 1) mx = fmaxf(mx, __shfl_xor(mx, o));
  float s = act ? __expf(v - mx) : 0.f;
#pragma unroll
  for (int o = 32; o > 0; o >>= 1) s += __shfl_xor(s, o);
  float logZ = mx + __logf(s);
  float part = 0.f;
  int cntm = 0;
  for (int t = lane; t < 512; t += 64) cntm += (lab[t] != -1) ? 1 : 0;
  for (int t = 1 + lane; t < 512; t += 64) {
    int tg = lab[t];
    if (tg != -1) {
      int tp = lab[t - 1];
      int tgc = min(max(tg, 0), 19);
      int tpc = min(max(tp, 0), 19);
      part += trans[tpc * 20 + tgc] + emb[t * 20 + tgc];
    }
  }
#pragma unroll
  for (int o = 32; o > 0; o >>= 1) {
    part += __shfl_xor(part, o);
    cntm += __shfl_xor(cntm, o);
  }
  if (lane == 0) {
    int t0c = min(max(lab[0], 0), 19);
    float score = startt[t0c] + emb[t0c] + part;
    int last = max(cntm - 1, 0);
    int tlc = min(max(lab[last], 0), 19);
    score += endt[tlc];
    float llh = score - logZ;
    atomicAdd(out, llh * (-1.f / 64.f));
  }
}

// ---------------------------------------------------------------------------
extern "C" void kernel_launch(void* const* d_in, const int* in_sizes, int n_in,
                              void* d_out, int out_size, void* d_ws, size_t ws_size,
                              hipStream_t stream) {
  const float* x      = (const float*)d_in[0];
  const int* labels   = (const int*)d_in[1];
  const float* Wih0   = (const float*)d_in[3];
  const float* Whh0   = (const float*)d_in[4];
  const float* bih0   = (const float*)d_in[5];
  const float* bhh0   = (const float*)d_in[6];
  const float* Wih1   = (const float*)d_in[7];
  const float* Whh1   = (const float*)d_in[8];
  const float* bih1   = (const float*)d_in[9];
  const float* bhh1   = (const float*)d_in[10];
  const float* fcw    = (const float*)d_in[11];
  const float* fcb    = (const float*)d_in[12];
  const float* startt = (const float*)d_in[13];
  const float* endt   = (const float*)d_in[14];
  const float* trans  = (const float*)d_in[15];
  float* out = (float*)d_out;

  char* ws = (char*)d_ws;
  size_t off = 0;
  auto alloc = [&](size_t bytes) -> void* {
    void* p = ws + off;
    off = (off + bytes + 255) & ~(size_t)255;
    return p;
  };
  unsigned short* h1_all = (unsigned short*)alloc(33554432ull * 2);  // 64 MB
  unsigned short* Whh0_b = (unsigned short*)alloc(4194304ull * 2);
  unsigned short* Wih0_b = (unsigned short*)alloc(2097152ull * 2);
  unsigned short* Whh1_b = (unsigned short*)alloc(4194304ull * 2);
  unsigned short* Wih1_b = (unsigned short*)alloc(4194304ull * 2);
  unsigned short* fcw_b  = (unsigned short*)alloc(20480ull * 2);
  float* bias0           = (float*)alloc(4096 * 4);
  float* bias1           = (float*)alloc(4096 * 4);
  unsigned short* h0r    = (unsigned short*)alloc(131072ull * 2);
  unsigned short* h1r    = (unsigned short*)alloc(131072ull * 2);
  float* em              = (float*)alloc(32768ull * 20 * 4);
  unsigned* flags        = (unsigned*)alloc(2048);

  if (off > ws_size) {
    unsigned wsmb = (unsigned)(ws_size >> 20);
    fallback_k<<<1, 1, 0, stream>>>(out, wsmb);
    return;
  }

  hipMemsetAsync(flags, 0, 2048, stream);
  hipMemsetAsync(d_out, 0, sizeof(float), stream);

  cvt_bf16<<<4096, 256, 0, stream>>>(Whh0, Whh0_b, 4194304);
  cvt_bf16<<<2048, 256, 0, stream>>>(Wih0, Wih0_b, 2097152);
  cvt_bf16<<<4096, 256, 0, stream>>>(Whh1, Whh1_b, 4194304);
  cvt_bf16<<<4096, 256, 0, stream>>>(Wih1, Wih1_b, 4194304);
  cvt_bf16<<<20, 256, 0, stream>>>(fcw, fcw_b, 20480);
  add_vec<<<16, 256, 0, stream>>>(bih0, bhh0, bias0, 4096);
  add_vec<<<16, 256, 0, stream>>>(bih1, bhh1, bias1, 4096);

  {
    static bool attr_set = false;   // host-side only; same work every call
    if (!attr_set) {
      hipFuncSetAttribute((const void*)lstm_fused,
                          hipFuncAttributeMaxDynamicSharedMemorySize, 131072);
      attr_set = true;
    }
    void* args[] = {(void*)&x, (void*)&Whh0_b, (void*)&Wih0_b, (void*)&Whh1_b,
                    (void*)&Wih1_b, (void*)&bias0, (void*)&bias1,
                    (void*)&h1_all, (void*)&h0r, (void*)&h1r, (void*)&flags};
    hipLaunchCooperativeKernel((void*)lstm_fused, dim3(256), dim3(256), args,
                               131072, stream);
  }
  emis_k<<<512, 256, 0, stream>>>(h1_all, fcw_b, fcb, em);
  crf_k<<<16, 256, 0, stream>>>(em, labels, startt, endt, trans, out);
}